// Round 9
// baseline (3706.372 us; speedup 1.0000x reference)
//
#include <hip/hip_runtime.h>

#define T_STEPS 64
#define BATCH   128
#define HID     1024
#define H3      3072
#define EMBD    1024
#define SLEN    128
#define BH      (BATCH * HID)

typedef __attribute__((ext_vector_type(8))) short short8;
typedef __attribute__((ext_vector_type(4))) float f32x4;

__device__ __forceinline__ unsigned short f2bf(float x) {
    unsigned int u = __float_as_uint(x);
    unsigned int r = (u + 0x7fffu + ((u >> 16) & 1u)) >> 16;
    return (unsigned short)r;
}
__device__ __forceinline__ float bf2f(unsigned short h) {
    return __uint_as_float(((unsigned int)h) << 16);
}
__device__ __forceinline__ unsigned int pk(unsigned short a, unsigned short b) {
    return (unsigned int)a | ((unsigned int)b << 16);
}
__device__ __forceinline__ void cvt8(const float4& x, const float4& y,
                                     uint4& H, uint4& L) {
    unsigned short h0 = f2bf(x.x), h1 = f2bf(x.y), h2 = f2bf(x.z), h3 = f2bf(x.w);
    unsigned short h4 = f2bf(y.x), h5 = f2bf(y.y), h6 = f2bf(y.z), h7 = f2bf(y.w);
    unsigned short l0 = f2bf(x.x - bf2f(h0)), l1 = f2bf(x.y - bf2f(h1));
    unsigned short l2 = f2bf(x.z - bf2f(h2)), l3 = f2bf(x.w - bf2f(h3));
    unsigned short l4 = f2bf(y.x - bf2f(h4)), l5 = f2bf(y.y - bf2f(h5));
    unsigned short l6 = f2bf(y.z - bf2f(h6)), l7 = f2bf(y.w - bf2f(h7));
    H = make_uint4(pk(h0,h1), pk(h2,h3), pk(h4,h5), pk(h6,h7));
    L = make_uint4(pk(l0,l1), pk(l2,l3), pk(l4,l5), pk(l6,l7));
}
__device__ __forceinline__ float sigf(float x) {
    return 1.f / (1.f + __expf(-x));
}
__device__ __forceinline__ short8 ldg8(const short* p) {
    return *(const short8*)p;
}
// fragment-linear index within a 128x1024 plane: lane = ((k>>3)&3)*16 + (r&15)
__device__ __forceinline__ size_t flidx(int r, int k) {
    return ((size_t)((r >> 4) * 32 + (k >> 5)) << 9)
         + ((((k >> 3) & 3) * 16 + (r & 15)) << 3) + (k & 7);
}

#define MF(A, B, ACC) ACC = __builtin_amdgcn_mfma_f32_16x16x32_bf16(A, B, ACC, 0, 0, 0)
#define TRI(AH, AL, WH, WL, ACC)  MF(AH, WL, ACC); MF(AL, WH, ACC); MF(AH, WH, ACC);

// ============== conversion kernels (once per call) ==============
__global__ __launch_bounds__(256) void conv_planes_k(
    const float* __restrict__ src, short* __restrict__ hi, short* __restrict__ lo)
{
    const long i8 = (long)blockIdx.x * 256 + threadIdx.x;
    float4 x = ((const float4*)src)[i8 * 2];
    float4 y = ((const float4*)src)[i8 * 2 + 1];
    uint4 H, L; cvt8(x, y, H, L);
    ((uint4*)hi)[i8] = H; ((uint4*)lo)[i8] = L;
}

__global__ __launch_bounds__(256) void conv_gather_k(
    const float* __restrict__ emb, const int* __restrict__ input,
    short* __restrict__ hi, short* __restrict__ lo)
{
    const long i8 = (long)blockIdx.x * 256 + threadIdx.x;
    const int c8 = (int)(i8 & 127);
    const long row = i8 >> 7;
    const float* s = emb + (size_t)input[row] * 1024 + c8 * 8;
    float4 x = ((const float4*)s)[0];
    float4 y = ((const float4*)s)[1];
    uint4 H, L; cvt8(x, y, H, L);
    ((uint4*)hi)[i8] = H; ((uint4*)lo)[i8] = L;
}

// f32 [N][1024] -> fragment-linear bf16 planes (N = 3072 rows/cols of W)
template<bool LO>
__global__ __launch_bounds__(256) void conv_fl_w(
    const float* __restrict__ src, short* __restrict__ hi, short* __restrict__ lo)
{
    const long g = (long)blockIdx.x * 256 + threadIdx.x;
    const int col = (int)(g >> 7);
    const int kb = (int)(g & 127) * 8;
    const float* s = src + (size_t)col * 1024 + kb;
    float4 x = ((const float4*)s)[0];
    float4 y = ((const float4*)s)[1];
    uint4 H, L; cvt8(x, y, H, L);
    const size_t fi = (((size_t)(col >> 4) * 32 + (kb >> 5)) << 9)
                    + ((((kb >> 3) & 3) * 16 + (col & 15)) << 3);
    *(uint4*)(hi + fi) = H;
    if (LO) *(uint4*)(lo + fi) = L;
}

// h_in f32 [2][128][1024] -> FL planes per layer
__global__ __launch_bounds__(256) void conv_fl_h(
    const float* __restrict__ src, short* __restrict__ hi, short* __restrict__ lo)
{
    const long g = (long)blockIdx.x * 256 + threadIdx.x;   // 32768 groups
    const int row = (int)(g >> 7);        // 0..255
    const int kb = (int)(g & 127) * 8;
    const int lay = row >> 7, r = row & 127;
    const float* s = src + (size_t)row * 1024 + kb;
    float4 x = ((const float4*)s)[0];
    float4 y = ((const float4*)s)[1];
    uint4 H, L; cvt8(x, y, H, L);
    const size_t fi = (size_t)lay * BH + (((size_t)(r >> 4) * 32 + (kb >> 5)) << 9)
                    + ((((kb >> 3) & 3) * 16 + (r & 15)) << 3);
    *(uint4*)(hi + fi) = H;
    *(uint4*)(lo + fi) = L;
}

// ============== big batched GEMM: 128x128 block tile ==============
// MODE 0: outf = acc + bias     MODE 1: planes store (+bias if given)
// MODE 2: outf = tanh(acc)      WLO: drop Ah*Wl term.
template<int MODE, bool CONCAT, bool WLO>
__global__ __launch_bounds__(256, 2) void gemm_big(
    const short* __restrict__ A1h, const short* __restrict__ A1l,
    const short* __restrict__ A2h, const short* __restrict__ A2l,
    const short* __restrict__ Wh,  const short* __restrict__ Wl,
    int K, int nn,
    const float* __restrict__ bias,
    float* __restrict__ outf, short* __restrict__ outh, short* __restrict__ outl,
    int ldo)
{
    extern __shared__ short sm[];
    short* Asm = sm;
    short* Wsm = sm + 16384;
    const int tid = threadIdx.x;
    const int wv = tid >> 6, l = tid & 63;
    const int mq = wv >> 1, nq = wv & 1;
    const int gl = l >> 4, r16 = l & 15;

    const int cpx = gridDim.x >> 3;
    const int id = blockIdx.x;
    const int swz = (id & 7) * cpx + (id >> 3);
    const int bm = swz / nn, bn = swz % nn;
    const long Rbase = (long)bm * 128;
    const int  Cbase = bn * 128;

    const int lda = CONCAT ? (K >> 1) : K;
    const int NC = K >> 5;
    const int NCh = NC >> 1;

    const short *aP1[4], *aP2[4], *wP[4];
    int slda[4];
    #pragma unroll
    for (int j = 0; j < 4; ++j) {
        const int s = tid + j * 256;
        const int pl = s >> 9, sp = s & 511;
        const int row = ((sp >> 6) << 4) | (sp & 15);
        const int kg = (sp >> 4) & 3;
        slda[j] = s * 8;
        const short* a1 = pl ? A1l : A1h;
        aP1[j] = a1 + (Rbase + row) * (long)lda + kg * 8;
        if (CONCAT) {
            const short* a2 = pl ? A2l : A2h;
            aP2[j] = a2 + (Rbase + row) * (long)lda + kg * 8;
        } else aP2[j] = aP1[j];
        const short* wp = pl ? Wl : Wh;
        wP[j] = wp + ((long)Cbase + row) * (long)K + kg * 8;
    }

    f32x4 acc[4][4];
    #pragma unroll
    for (int i = 0; i < 4; ++i)
        #pragma unroll
        for (int j = 0; j < 4; ++j) acc[i][j] = (f32x4)0.f;

    short8 rA[4], rW[4];
    auto LOADC = [&](int c) {
        const bool p1 = !CONCAT || (c < NCh);
        const long ko = p1 ? (long)c * 32 : (long)c * 32 - (K >> 1);
        #pragma unroll
        for (int j = 0; j < 4; ++j) {
            rA[j] = *(const short8*)((p1 ? aP1[j] : aP2[j]) + ko);
            rW[j] = *(const short8*)(wP[j] + (long)c * 32);
        }
    };
    auto STORE = [&](int c) {
        const int b = (c & 1) << 13;
        #pragma unroll
        for (int j = 0; j < 4; ++j) {
            *(short8*)(Asm + b + slda[j]) = rA[j];
            *(short8*)(Wsm + b + slda[j]) = rW[j];
        }
    };

    LOADC(0); STORE(0); LOADC(1);
    __syncthreads();

    for (int c = 0; c < NC; ++c) {
        const int b = (c & 1) << 13;
        short8 ah[4], al[4], wh[4], wl[4];
        #pragma unroll
        for (int f = 0; f < 4; ++f) {
            const short* ab = Asm + b + ((mq * 4 + f) * 64 + l) * 8;
            ah[f] = *(const short8*)ab;
            al[f] = *(const short8*)(ab + 4096);
            const short* wb = Wsm + b + ((nq * 4 + f) * 64 + l) * 8;
            wh[f] = *(const short8*)wb;
            if (!WLO) wl[f] = *(const short8*)(wb + 4096);
        }
        if (c + 1 < NC) STORE(c + 1);
        if (c + 2 < NC) LOADC(c + 2);
        #pragma unroll
        for (int mf = 0; mf < 4; ++mf)
            #pragma unroll
            for (int nf = 0; nf < 4; ++nf) {
                if constexpr (WLO) {
                    MF(al[mf], wh[nf], acc[mf][nf]);
                    MF(ah[mf], wh[nf], acc[mf][nf]);
                } else {
                    TRI(ah[mf], al[mf], wh[nf], wl[nf], acc[mf][nf]);
                }
            }
        __syncthreads();
    }

    #pragma unroll
    for (int mf = 0; mf < 4; ++mf) {
        #pragma unroll
        for (int reg = 0; reg < 4; ++reg) {
            const long R = Rbase + mq * 64 + mf * 16 + gl * 4 + reg;
            #pragma unroll
            for (int nf = 0; nf < 4; ++nf) {
                const int col = Cbase + nq * 64 + nf * 16 + r16;
                float v = acc[mf][nf][reg];
                if constexpr (MODE == 0) {
                    outf[R * (long)ldo + col] = v + bias[col];
                } else if constexpr (MODE == 1) {
                    if (bias) v += bias[col];
                    const unsigned short hi = f2bf(v), lo = f2bf(v - bf2f(hi));
                    outh[R * (long)ldo + col] = (short)hi;
                    outl[R * (long)ldo + col] = (short)lo;
                } else {
                    outf[R * (long)ldo + col] = tanhf(v);
                }
            }
        }
    }
}

// ============== barrier-free fragment-streaming step kernel ==============
// 256 blocks x 256 thr; wave gw = blockIdx*4 + w; z = gw>>9.
// z0 task (cs, mt): h0_t gate. A = h0_{t-1} FL planes, W = whh0 FL hi (DUO).
// z1 task (cs, mt): h1_{t-1}. phase ih: A=h0_{t-1} FL, W=wih1 FL hi+lo (TRI);
//                   phase hh: A=h1_{t-2} FL, W=whh1 FL hi (DUO). n kept split.
struct SP2 {
    const short *hihF, *hilF;
    const float* h_in;
    const short *gih, *gil;
    const short *whh0F, *wih1Fh, *wih1Fl, *whh1F;
    const float *b_hh0, *b_ih1, *b_hh1;
    float *h0f, *h1f;
    short *h0Fh, *h0Fl, *h1Fh, *h1Fl, *h1ah, *h1al;
};

__global__ __launch_bounds__(256) void step2_k(int t, SP2 P)
{
    const int tid = threadIdx.x;
    const int w = tid >> 6, l = tid & 63;
    const int gw = blockIdx.x * 4 + w;
    const int z = gw >> 9;
    const int r = gw & 511;
    const int cs = r >> 3, mt = r & 7;
    const int gl = l >> 4, c16 = l & 15;
    const int jc = cs * 16 + c16;
    const size_t aOff = ((size_t)mt * 32 * 64 + l) * 8;   // + c*512

    if (z == 0) {
        if (t >= T_STEPS) return;
        const short* Ah = t ? P.h0Fh + (size_t)(t - 1) * BH : P.hihF;
        const short* Al = t ? P.h0Fl + (size_t)(t - 1) * BH : P.hilF;
        f32x4 a0 = (f32x4)0.f, a1 = (f32x4)0.f, a2 = (f32x4)0.f;
        #pragma unroll
        for (int c = 0; c < 32; ++c) {
            short8 ah = ldg8(Ah + aOff + c * 512);
            short8 al = ldg8(Al + aOff + c * 512);
            #pragma unroll
            for (int p = 0; p < 3; ++p) {
                const size_t wi = (((size_t)(p * 64 + cs) * 32 + c) << 9) + l * 8;
                short8 wh = ldg8(P.whh0F + wi);
                if (p == 0)      { MF(al, wh, a0); MF(ah, wh, a0); }
                else if (p == 1) { MF(al, wh, a1); MF(ah, wh, a1); }
                else             { MF(al, wh, a2); MF(ah, wh, a2); }
            }
        }
        const float b_r = P.b_hh0[jc], b_z = P.b_hh0[HID + jc], b_n = P.b_hh0[2 * HID + jc];
        const float* hp = t ? P.h0f + (size_t)((t - 1) & 1) * BH : P.h_in;
        float* ho = P.h0f + (size_t)(t & 1) * BH;
        short* oh = P.h0Fh + (size_t)t * BH;
        short* ol = P.h0Fl + (size_t)t * BH;
        #pragma unroll
        for (int reg = 0; reg < 4; ++reg) {
            const int R = mt * 16 + gl * 4 + reg;
            const size_t gR = ((size_t)t * 128 + R) * H3;
            const float gr = bf2f((unsigned short)P.gih[gR + jc]) + bf2f((unsigned short)P.gil[gR + jc]);
            const float gz = bf2f((unsigned short)P.gih[gR + HID + jc]) + bf2f((unsigned short)P.gil[gR + HID + jc]);
            const float gn = bf2f((unsigned short)P.gih[gR + 2 * HID + jc]) + bf2f((unsigned short)P.gil[gR + 2 * HID + jc]);
            const float rr = sigf(gr + a0[reg] + b_r);
            const float zz = sigf(gz + a1[reg] + b_z);
            const float nn = tanhf(gn + rr * (a2[reg] + b_n));
            const float h = (1.f - zz) * nn + zz * hp[(size_t)R * HID + jc];
            ho[(size_t)R * HID + jc] = h;
            const unsigned short hb = f2bf(h), lb = f2bf(h - bf2f(hb));
            const size_t fi = flidx(R, jc);
            oh[fi] = (short)hb; ol[fi] = (short)lb;
        }
    } else {
        const int s = t - 1;
        if (s < 0) return;
        const short* A1h = P.h0Fh + (size_t)s * BH;
        const short* A1l = P.h0Fl + (size_t)s * BH;
        const short* A2h = s ? P.h1Fh + (size_t)(s - 1) * BH : P.hihF + BH;
        const short* A2l = s ? P.h1Fl + (size_t)(s - 1) * BH : P.hilF + BH;
        f32x4 a0 = (f32x4)0.f, a1 = (f32x4)0.f, a2 = (f32x4)0.f, a3 = (f32x4)0.f;
        // phase ih: TRI with wih1 hi+lo
        #pragma unroll
        for (int c = 0; c < 32; ++c) {
            short8 ah = ldg8(A1h + aOff + c * 512);
            short8 al = ldg8(A1l + aOff + c * 512);
            #pragma unroll
            for (int p = 0; p < 3; ++p) {
                const size_t wi = (((size_t)(p * 64 + cs) * 32 + c) << 9) + l * 8;
                short8 wh = ldg8(P.wih1Fh + wi);
                short8 wl = ldg8(P.wih1Fl + wi);
                if (p == 0)      { TRI(ah, al, wh, wl, a0); }
                else if (p == 1) { TRI(ah, al, wh, wl, a1); }
                else             { TRI(ah, al, wh, wl, a2); }
            }
        }
        // phase hh: DUO with whh1 hi (n-part into a3)
        #pragma unroll
        for (int c = 0; c < 32; ++c) {
            short8 ah = ldg8(A2h + aOff + c * 512);
            short8 al = ldg8(A2l + aOff + c * 512);
            #pragma unroll
            for (int p = 0; p < 3; ++p) {
                const size_t wi = (((size_t)(p * 64 + cs) * 32 + c) << 9) + l * 8;
                short8 wh = ldg8(P.whh1F + wi);
                if (p == 0)      { MF(al, wh, a0); MF(ah, wh, a0); }
                else if (p == 1) { MF(al, wh, a1); MF(ah, wh, a1); }
                else             { MF(al, wh, a3); MF(ah, wh, a3); }
            }
        }
        const float bir = P.b_ih1[jc] + P.b_hh1[jc];
        const float biz = P.b_ih1[HID + jc] + P.b_hh1[HID + jc];
        const float bin = P.b_ih1[2 * HID + jc];
        const float bhn = P.b_hh1[2 * HID + jc];
        const float* hp = s ? P.h1f + (size_t)((s - 1) & 1) * BH : P.h_in + BH;
        float* ho = P.h1f + (size_t)(s & 1) * BH;
        short* oh = P.h1Fh + (size_t)s * BH;
        short* ol = P.h1Fl + (size_t)s * BH;
        short* rh = P.h1ah + (size_t)s * BH;
        short* rl = P.h1al + (size_t)s * BH;
        #pragma unroll
        for (int reg = 0; reg < 4; ++reg) {
            const int R = mt * 16 + gl * 4 + reg;
            const float rr = sigf(a0[reg] + bir);
            const float zz = sigf(a1[reg] + biz);
            const float nn = tanhf(a2[reg] + bin + rr * (a3[reg] + bhn));
            const float h = (1.f - zz) * nn + zz * hp[(size_t)R * HID + jc];
            ho[(size_t)R * HID + jc] = h;
            const unsigned short hb = f2bf(h), lb = f2bf(h - bf2f(hb));
            const size_t fi = flidx(R, jc);
            oh[fi] = (short)hb; ol[fi] = (short)lb;
            rh[(size_t)R * HID + jc] = (short)hb;
            rl[(size_t)R * HID + jc] = (short)lb;
        }
    }
}

// ============== batched attention scores + softmax (per b) ==============
__global__ __launch_bounds__(256) void scores_k(
    const short* __restrict__ Qh, const short* __restrict__ Ql,
    const short* __restrict__ Hh, const short* __restrict__ Hl,
    float* __restrict__ Pall)
{
    extern __shared__ short sm[];
    short* Asm = sm;
    short* Wsm = sm + 8192;
    const int b = blockIdx.x, tid = threadIdx.x;
    const int wv = tid >> 6, l = tid & 63;
    const int gl = l >> 4, cc = l & 15;

    const int arow = ((tid >> 6) & 3) * 16 + (tid & 15);
    const int ag   = (tid >> 4) & 3;
    const short* qhp = Qh + ((long)arow * BATCH + b) * HID + ag * 8;
    const short* qlp = Ql + ((long)arow * BATCH + b) * HID + ag * 8;
    const int aLds = tid * 8;

    const short *whp[2], *wlp[2]; int wLds[2];
    #pragma unroll
    for (int i = 0; i < 2; ++i) {
        const int s = tid + i * 256;
        const int srow = ((s >> 6) & 7) * 16 + (s & 15);
        const int sg   = (s >> 4) & 3;
        whp[i] = Hh + ((long)srow * BATCH + b) * HID + sg * 8;
        wlp[i] = Hl + ((long)srow * BATCH + b) * HID + sg * 8;
        wLds[i] = s * 8;
    }

    f32x4 acc[8];
    #pragma unroll
    for (int i = 0; i < 8; ++i) acc[i] = (f32x4)0.f;

    short8 rAh, rAl, rWh[2], rWl[2];
    auto LOADC = [&](int c) {
        rAh = *(const short8*)(qhp + c * 32);
        rAl = *(const short8*)(qlp + c * 32);
        #pragma unroll
        for (int i = 0; i < 2; ++i) {
            rWh[i] = *(const short8*)(whp[i] + c * 32);
            rWl[i] = *(const short8*)(wlp[i] + c * 32);
        }
    };
    auto STORE = [&](int c) {
        const int bb = c & 1;
        *(short8*)(Asm + bb * 4096 + aLds) = rAh;
        *(short8*)(Asm + bb * 4096 + 2048 + aLds) = rAl;
        #pragma unroll
        for (int i = 0; i < 2; ++i) {
            *(short8*)(Wsm + bb * 8192 + wLds[i]) = rWh[i];
            *(short8*)(Wsm + bb * 8192 + 4096 + wLds[i]) = rWl[i];
        }
    };

    LOADC(0); STORE(0); LOADC(1);
    __syncthreads();
    for (int c = 0; c < 32; ++c) {
        const int bb = c & 1;
        const short* abp = Asm + bb * 4096 + (wv * 64 + l) * 8;
        short8 ah = *(const short8*)abp;
        short8 al = *(const short8*)(abp + 2048);
        if (c + 1 < 32) STORE(c + 1);
        if (c + 2 < 32) LOADC(c + 2);
        #pragma unroll
        for (int jt = 0; jt < 8; ++jt) {
            const short* wbp = Wsm + bb * 8192 + (jt * 64 + l) * 8;
            short8 wh = *(const short8*)wbp;
            short8 wl = *(const short8*)(wbp + 4096);
            TRI(ah, al, wh, wl, acc[jt]);
        }
        __syncthreads();
    }

    #pragma unroll
    for (int reg = 0; reg < 4; ++reg) {
        float m = acc[0][reg];
        #pragma unroll
        for (int jt = 1; jt < 8; ++jt) m = fmaxf(m, acc[jt][reg]);
        #pragma unroll
        for (int off = 1; off < 16; off <<= 1) m = fmaxf(m, __shfl_xor(m, off));
        float e[8], ssum = 0.f;
        #pragma unroll
        for (int jt = 0; jt < 8; ++jt) { e[jt] = __expf(acc[jt][reg] - m); ssum += e[jt]; }
        #pragma unroll
        for (int off = 1; off < 16; off <<= 1) ssum += __shfl_xor(ssum, off);
        const float inv = 1.f / ssum;
        const int t = wv * 16 + gl * 4 + reg;
        #pragma unroll
        for (int jt = 0; jt < 8; ++jt)
            Pall[((long)t * BATCH + b) * SLEN + jt * 16 + cc] = e[jt] * inv;
    }
}

__global__ __launch_bounds__(256) void ctx_k(
    const float* __restrict__ Pall, const float* __restrict__ H,
    short* __restrict__ Ch, short* __restrict__ Cl)
{
    __shared__ float Ps[T_STEPS * SLEN];
    const int b = blockIdx.x, ht = blockIdx.y, tid = threadIdx.x;
    for (int i = 0; i < 32; ++i) {
        const int idx = i * 256 + tid;
        const int t = idx >> 7, s = idx & 127;
        Ps[idx] = Pall[((long)t * BATCH + b) * SLEN + s];
    }
    __syncthreads();
    const int col = ht * 256 + tid;
    for (int tg = 0; tg < 4; ++tg) {
        float a[16];
        #pragma unroll
        for (int j = 0; j < 16; ++j) a[j] = 0.f;
        for (int s = 0; s < SLEN; ++s) {
            const float hv = H[((long)s * BATCH + b) * HID + col];
            #pragma unroll
            for (int j = 0; j < 16; ++j)
                a[j] = fmaf(Ps[(tg * 16 + j) * SLEN + s], hv, a[j]);
        }
        #pragma unroll
        for (int j = 0; j < 16; ++j) {
            const long row = (long)(tg * 16 + j) * BATCH + b;
            const unsigned short hi = f2bf(a[j]);
            const unsigned short lo = f2bf(a[j] - bf2f(hi));
            Ch[row * HID + col] = (short)hi;
            Cl[row * HID + col] = (short)lo;
        }
    }
}

// =========================== launch ===========================
extern "C" void kernel_launch(void* const* d_in, const int* in_sizes, int n_in,
                              void* d_out, int out_size, void* d_ws, size_t ws_size,
                              hipStream_t stream)
{
    const int*   input = (const int*)  d_in[0];
    const float* h_in  = (const float*)d_in[1];
    const float* Hbuf  = (const float*)d_in[2];
    const float* emb   = (const float*)d_in[3];
    const float* w_ih  = (const float*)d_in[4];
    const float* w_hh  = (const float*)d_in[5];
    const float* b_ih  = (const float*)d_in[6];
    const float* b_hh  = (const float*)d_in[7];
    const float* L1    = (const float*)d_in[8];
    const float* L2    = (const float*)d_in[9];

    float* out = (float*)d_out;

    char* basep = (char*)d_ws;
    size_t off = 0;
    auto alloc = [&](size_t bytes) -> char* {
        off = (off + 255) & ~(size_t)255;
        char* p = basep + off; off += bytes; return p;
    };
    short* wih0h = (short*)alloc(3145728L*2); short* wih0l = (short*)alloc(3145728L*2);
    short* l1h   = (short*)alloc(1048576L*2); short* l1l   = (short*)alloc(1048576L*2);
    short* l2h   = (short*)alloc(2097152L*2); short* l2l   = (short*)alloc(2097152L*2);
    short* Hh    = (short*)alloc(16777216L*2); short* Hl   = (short*)alloc(16777216L*2);
    short* hihF  = (short*)alloc(262144L*2);  short* hilF  = (short*)alloc(262144L*2);
    short* h0Fh  = (short*)alloc(8388608L*2); short* h0Fl  = (short*)alloc(8388608L*2);
    short* h1Fh  = (short*)alloc(8388608L*2); short* h1Fl  = (short*)alloc(8388608L*2);
    short* h1ah  = (short*)alloc(8388608L*2); short* h1al  = (short*)alloc(8388608L*2);
    short* eqh   = (short*)alloc(8388608L*2); short* eql   = (short*)alloc(8388608L*2);
    short* gi0h  = (short*)alloc(25165824L*2); short* gi0l = (short*)alloc(25165824L*2);
    short* whh0F = (short*)alloc(3145728L*2);
    short* wih1Fh= (short*)alloc(3145728L*2); short* wih1Fl= (short*)alloc(3145728L*2);
    short* whh1F = (short*)alloc(3145728L*2);
    float* h0f   = (float*)alloc(524288L*4);
    float* h1f   = (float*)alloc(524288L*4);
    float* Pall  = (float*)alloc(1048576L*4);
    short* ctxh  = gi0h;                       // gi planes dead after step loop
    short* ctxl  = gi0h + 8388608L;

    const dim3 blk(256);
    const size_t SMB = 32768 * sizeof(short);   // 64 KB for gemm_big

    // ---- phase 0: conversions ----
    conv_planes_k<<<1536, blk, 0, stream>>>(w_ih, wih0h, wih0l);
    conv_planes_k<<<512,  blk, 0, stream>>>(L1, l1h, l1l);
    conv_planes_k<<<1024, blk, 0, stream>>>(L2, l2h, l2l);
    conv_planes_k<<<8192, blk, 0, stream>>>(Hbuf, Hh, Hl);
    conv_gather_k<<<4096, blk, 0, stream>>>(emb, input, eqh, eql);
    conv_fl_h<<<128, blk, 0, stream>>>(h_in, hihF, hilF);
    conv_fl_w<false><<<1536, blk, 0, stream>>>(w_hh, whh0F, nullptr);
    conv_fl_w<true><<<1536, blk, 0, stream>>>(w_ih + 3145728L, wih1Fh, wih1Fl);
    conv_fl_w<false><<<1536, blk, 0, stream>>>(w_hh + 3145728L, whh1F, nullptr);

    // gi0_all = E @ w_ih0^T + b_ih0 -> bf16 hi/lo planes (8192 x 3072)
    gemm_big<1, false, true><<<dim3(1536), blk, SMB, stream>>>(
        eqh, eql, nullptr, nullptr, wih0h, wih0l, 1024, 24,
        b_ih, nullptr, gi0h, gi0l, H3);

    // ---- pipelined recurrence: 65 barrier-free launches ----
    SP2 sp;
    sp.hihF = hihF; sp.hilF = hilF; sp.h_in = h_in;
    sp.gih = gi0h; sp.gil = gi0l;
    sp.whh0F = whh0F; sp.wih1Fh = wih1Fh; sp.wih1Fl = wih1Fl; sp.whh1F = whh1F;
    sp.b_hh0 = b_hh; sp.b_ih1 = b_ih + H3; sp.b_hh1 = b_hh + H3;
    sp.h0f = h0f; sp.h1f = h1f;
    sp.h0Fh = h0Fh; sp.h0Fl = h0Fl; sp.h1Fh = h1Fh; sp.h1Fl = h1Fl;
    sp.h1ah = h1ah; sp.h1al = h1al;
    for (int t = 0; t <= T_STEPS; ++t)
        step2_k<<<dim3(256), blk, 0, stream>>>(t, sp);

    // ---- batched attention + output ----
    gemm_big<1, false, false><<<dim3(512), blk, SMB, stream>>>(
        h1ah, h1al, nullptr, nullptr, l1h, l1l, 1024, 8,
        nullptr, nullptr, eqh, eql, HID);
    scores_k<<<dim3(BATCH), blk, 49152, stream>>>(eqh, eql, Hh, Hl, Pall);
    ctx_k<<<dim3(BATCH, 4), blk, 0, stream>>>(Pall, Hbuf, ctxh, ctxl);
    gemm_big<2, true, false><<<dim3(512), blk, SMB, stream>>>(
        ctxh, ctxl, h1ah, h1al, l2h, l2l, 2048, 8,
        nullptr, out, nullptr, nullptr, HID);

    hipMemcpyAsync(out + (long)T_STEPS * BH, h0f + BH, (size_t)BH * 4,
                   hipMemcpyDeviceToDevice, stream);
    hipMemcpyAsync(out + (long)T_STEPS * BH + BH, h1f + BH, (size_t)BH * 4,
                   hipMemcpyDeviceToDevice, stream);
}